// Round 4
// baseline (961.875 us; speedup 1.0000x reference)
//
#include <hip/hip_runtime.h>
#include <stdint.h>
#include <stddef.h>

// Problem: out = x @ base_kernel + bias + 2.0 * (x @ kron(lora_A@lora_B, O))
// Folded:  out = x @ (base_kernel + 2.0*kron(A@B, O)) + bias  -- ONE bf16 GEMM.
//
// R4 == R3 resubmitted (R3 hit a GPU-acquisition timeout; never ran).
// GEMM: m201-style 4-fine-phases/K-tile schedule: per phase {ds-read subtile
// frags; stage one 2-load group; vmcnt(4); barrier; lgkmcnt(0); setprio+16 MFMA;
// barrier}. prep_w fully vectorized (float4 loads, 16B bf16x8 stores).

#define M_TOT 16384
#define K_TOT 4096
#define N_TOT 4096
#define SCALING 2.0f
#define NT (K_TOT / 64)   // 64 K-tiles of BK=64 (two 32-wide k-subtiles each)

typedef __attribute__((ext_vector_type(8))) short bf16x8;   // 8 bf16 = 4 VGPRs
typedef __attribute__((ext_vector_type(4))) float floatx4;  // MFMA C/D frag
typedef __attribute__((ext_vector_type(4))) unsigned int uint4v;  // 16B store

__device__ __forceinline__ unsigned short f32_to_bf16(float f) {
  union { float f; unsigned int u; } v; v.f = f;
  unsigned int r = 0x7fffu + ((v.u >> 16) & 1u);  // round-to-nearest-even
  return (unsigned short)((v.u + r) >> 16);
}

__device__ __forceinline__ void async_copy16(const void* gsrc, void* ldst) {
  __builtin_amdgcn_global_load_lds(
      (const __attribute__((address_space(1))) void*)(uintptr_t)gsrc,
      (__attribute__((address_space(3))) void*)(uintptr_t)ldst,
      16, 0, 0);
}

// ---- Kernel 1: wl = SCALING * (lora_A @ lora_B), 16x16, fp32 ----
__global__ void wleft_kernel(const float* __restrict__ A, const float* __restrict__ B,
                             float* __restrict__ wl) {
  int i = threadIdx.x >> 4, j = threadIdx.x & 15;
  float s = 0.f;
#pragma unroll
  for (int k = 0; k < 16; ++k) s += A[i * 16 + k] * B[k * 16 + j];
  wl[threadIdx.x] = s * SCALING;
}

// ---- Kernel 2: Wt[n][k] = bf16( base[k][n] + wl * O[k&255][n&255] ), vectorized ----
// 64x64 tile. wl index is constant per tile (64-tile nests inside the 256-block).
// Loads: float4 (coalesced). LDS [64][65]: write banks (row+col)%32 -> 2-way free;
// read banks (8*kc+j*65+n)%32 == (8kc+n+j)%32 -> 2-way free. Stores: ushort8 = 16B.
__global__ void prep_w_kernel(const float* __restrict__ base, const float* __restrict__ O,
                              const float* __restrict__ wl, unsigned short* __restrict__ Wt) {
  __shared__ float tile[64][65];
  const int tid = threadIdx.x;  // 256
  const int n0 = blockIdx.x * 64, k0 = blockIdx.y * 64;
  const float wlv = wl[((k0 >> 8) << 4) + (n0 >> 8)];
  const float* Obase = O + ((size_t)(k0 & 255) << 8) + (n0 & 255);
#pragma unroll
  for (int rep = 0; rep < 4; ++rep) {
    int idx = rep * 256 + tid;
    int row = idx >> 4, c4 = (idx & 15) * 4;
    float4 b4 = *(const float4*)(base + (size_t)(k0 + row) * N_TOT + n0 + c4);
    float4 o4 = *(const float4*)(Obase + (size_t)row * 256 + c4);
    tile[row][c4 + 0] = b4.x + wlv * o4.x;
    tile[row][c4 + 1] = b4.y + wlv * o4.y;
    tile[row][c4 + 2] = b4.z + wlv * o4.z;
    tile[row][c4 + 3] = b4.w + wlv * o4.w;
  }
  __syncthreads();
#pragma unroll
  for (int rep = 0; rep < 2; ++rep) {
    int idx = rep * 256 + tid;
    int n = idx >> 3, kc = (idx & 7) * 8;
    union { uint4v v; unsigned short h[8]; } u;
#pragma unroll
    for (int j = 0; j < 8; ++j) u.h[j] = f32_to_bf16(tile[kc + j][n]);
    *(uint4v*)(Wt + (size_t)(n0 + n) * K_TOT + k0 + kc) = u.v;
  }
}

// ---- Kernel 3: x f32 -> bf16, 8 elems/thread ----
__global__ void cvt_x_kernel(const float* __restrict__ x, unsigned short* __restrict__ xb) {
  size_t i = ((size_t)blockIdx.x * blockDim.x + threadIdx.x) * 8;
  float4 a = *(const float4*)(x + i);
  float4 b = *(const float4*)(x + i + 4);
  union { bf16x8 v; unsigned short h[8]; } u;
  u.h[0] = f32_to_bf16(a.x); u.h[1] = f32_to_bf16(a.y);
  u.h[2] = f32_to_bf16(a.z); u.h[3] = f32_to_bf16(a.w);
  u.h[4] = f32_to_bf16(b.x); u.h[5] = f32_to_bf16(b.y);
  u.h[6] = f32_to_bf16(b.z); u.h[7] = f32_to_bf16(b.w);
  *(bf16x8*)(xb + i) = u.v;
}

// ---- Kernel 4: C = Xb(M x K) @ Wt(N x K)^T + bias ----
// Geometry/LDS/swizzle identical to R2 (proven: 0 bank conflicts). Schedule is
// m201's 4-phase/K-tile fine interleave:
//   P(t,0): read B-ks0(4) + A-ks0 m0-3(4);  stage G(t+1,0A)
//   P(t,1): read A-ks0 m4-7(4);             stage G(t+1,0B)
//   P(t,2): read B-ks1(4) + A-ks1 m0-3(4);  stage G(t+1,1A)
//   P(t,3): read A-ks1 m4-7(4);             stage G(t+1,1B)
// each followed by: vmcnt(4); s_barrier; lgkmcnt(0); setprio(1); 16 MFMA;
// setprio(0); s_barrier.
// Landing proof (issue order G(t,0A),G(t,0B),G(t,1A),G(t,1B) at P(t-1,0..3)):
// vmcnt(4) leaves exactly the 2 newest groups outstanding, so at each phase end
// every group read in the NEXT phase has landed (reads at phase start follow the
// previous phase's vmcnt+barrier). Forced-landing slack = 2 phases (~1700 cyc)
// >= 900 cyc HBM latency. Slot overwrite: every stage issues >= 2 barriers
// after its slot's last reader.
__global__ __launch_bounds__(512, 2) void gemm256_kernel(
    const unsigned short* __restrict__ Xb, const unsigned short* __restrict__ Wt,
    const float* __restrict__ bias, float* __restrict__ out) {
  __shared__ __align__(16) unsigned short lds[65536];  // 128 KiB

  const int tid = threadIdx.x;
  const int wave = tid >> 6, lane = tid & 63;
  const int quad = lane >> 4, lm = lane & 15;
  const int wm = wave >> 2, wn = wave & 3;  // 2 x 4 wave grid, per-wave 128(M) x 64(N)

  // T1: bijective XCD swizzle (grid 1024, divisible by 8).
  const int wg = blockIdx.x;
  const int swz = (wg & 7) * (1024 / 8) + (wg >> 3);
  const int m0 = (swz >> 4) * 256;  // 64 M-panels
  const int n0 = (swz & 15) * 256;  // 16 N-panels

  // Staging source (pre-swizzled gather), identical to R2.
  const int sch = (tid & 7) ^ ((tid >> 3) & 7);
  const int rowoff = 2 * (tid >> 3) + (sch >> 2);
  const int koff = (sch & 3) * 8;
  const unsigned short* srcA = Xb + (size_t)(m0 + rowoff) * K_TOT + koff;
  const unsigned short* srcB = Wt + (size_t)(n0 + rowoff) * K_TOT + koff;

  // Read-side swizzled offsets (shorts), identical to R2.
  const int pch = (((lm & 1) << 2) | quad) ^ (lm >> 1);
  const int aoff = wm * 4096 + (lm >> 1) * 64 + pch * 8;  // + i*512 per m-frag
  const int boff = wn * 2048 + (lm >> 1) * 64 + pch * 8;  // + j*512 per n-frag

  floatx4 acc[8][4];
#pragma unroll
  for (int i = 0; i < 8; ++i)
#pragma unroll
    for (int j = 0; j < 4; ++j) acc[i][j] = (floatx4){0.f, 0.f, 0.f, 0.f};

  bf16x8 af[4], bf[4];

#define STAGE_A(tt, ss) do {                                                     \
    unsigned short* la = lds + ((((tt) & 1) * 2 + (ss)) * 8192) + tid * 8;       \
    size_t kk = (size_t)(tt) * 64 + (ss) * 32;                                   \
    async_copy16(srcA + kk, la);                                                 \
    async_copy16(srcA + kk + (size_t)128 * K_TOT, la + 4096);                    \
  } while (0)

#define STAGE_B(tt, ss) do {                                                     \
    unsigned short* la = lds + 32768 + ((((tt) & 1) * 2 + (ss)) * 8192) + tid * 8; \
    size_t kk = (size_t)(tt) * 64 + (ss) * 32;                                   \
    async_copy16(srcB + kk, la);                                                 \
    async_copy16(srcB + kk + (size_t)128 * K_TOT, la + 4096);                    \
  } while (0)

#define LOADB(tt, ss) do {                                                       \
    const unsigned short* Bb = lds + 32768 + ((((tt) & 1) * 2 + (ss)) * 8192) + boff; \
    _Pragma("unroll") for (int j = 0; j < 4; ++j)                                \
      bf[j] = *(const bf16x8*)(Bb + j * 512);                                    \
  } while (0)

#define LOADA(tt, ss, h) do {                                                    \
    const unsigned short* Ab = lds + ((((tt) & 1) * 2 + (ss)) * 8192) + aoff;    \
    _Pragma("unroll") for (int i = 0; i < 4; ++i)                                \
      af[i] = *(const bf16x8*)(Ab + ((h) * 4 + i) * 512);                        \
  } while (0)

#define MFMA16(h) do {                                                           \
    __builtin_amdgcn_s_setprio(1);                                               \
    _Pragma("unroll") for (int i = 0; i < 4; ++i)                                \
      _Pragma("unroll") for (int j = 0; j < 4; ++j)                              \
        acc[(h) * 4 + i][j] =                                                    \
            __builtin_amdgcn_mfma_f32_16x16x32_bf16(af[i], bf[j], acc[(h) * 4 + i][j], 0, 0, 0); \
    __builtin_amdgcn_s_setprio(0);                                               \
  } while (0)

// vmcnt(N) -> barrier -> lgkmcnt(0): memory-clobbered asm fences on both sides
// of s_barrier (rule 18: LLVM does not model s_barrier as a memory fence).
#define SYNC1(n) do {                                                            \
    asm volatile("s_waitcnt vmcnt(" #n ")" ::: "memory");                        \
    __builtin_amdgcn_s_barrier();                                                \
    asm volatile("s_waitcnt lgkmcnt(0)" ::: "memory");                           \
  } while (0)

#define BAR2() do {                                                              \
    __builtin_amdgcn_s_barrier();                                                \
    asm volatile("" ::: "memory");                                               \
  } while (0)

  // Prologue: stage full tile 0, guarantee its ks0 groups landed.
  STAGE_A(0, 0);
  STAGE_B(0, 0);
  STAGE_A(0, 1);
  STAGE_B(0, 1);
  asm volatile("s_waitcnt vmcnt(4)" ::: "memory");  // G(0,0A),G(0,0B) landed
  __builtin_amdgcn_s_barrier();
  asm volatile("" ::: "memory");

  for (int t = 0; t < NT - 1; ++t) {
    // P0: B-ks0 + A-ks0 m0-3 ; stage next A-ks0
    LOADB(t, 0); LOADA(t, 0, 0);
    STAGE_A(t + 1, 0);
    SYNC1(4);
    MFMA16(0);
    BAR2();
    // P1: A-ks0 m4-7 ; stage next B-ks0
    LOADA(t, 0, 1);
    STAGE_B(t + 1, 0);
    SYNC1(4);
    MFMA16(1);
    BAR2();
    // P2: B-ks1 + A-ks1 m0-3 ; stage next A-ks1
    LOADB(t, 1); LOADA(t, 1, 0);
    STAGE_A(t + 1, 1);
    SYNC1(4);
    MFMA16(0);
    BAR2();
    // P3: A-ks1 m4-7 ; stage next B-ks1
    LOADA(t, 1, 1);
    STAGE_B(t + 1, 1);
    SYNC1(4);
    MFMA16(1);
    BAR2();
  }

  // Tail K-tile (t = NT-1): no staging; peel vmcnt 2 -> 0.
  {
    const int t = NT - 1;
    LOADB(t, 0); LOADA(t, 0, 0);
    SYNC1(2);
    MFMA16(0);
    BAR2();
    LOADA(t, 0, 1);
    SYNC1(0);
    MFMA16(1);
    BAR2();
    LOADB(t, 1); LOADA(t, 1, 0);
    __builtin_amdgcn_s_barrier();
    asm volatile("s_waitcnt lgkmcnt(0)" ::: "memory");
    MFMA16(0);
    BAR2();
    LOADA(t, 1, 1);
    asm volatile("s_waitcnt lgkmcnt(0)" ::: "memory");
    MFMA16(1);
  }

#undef STAGE_A
#undef STAGE_B
#undef LOADB
#undef LOADA
#undef MFMA16
#undef SYNC1
#undef BAR2

  // Epilogue: C/D layout col = lane&15, row = quad*4 + reg. Fuse bias.
#pragma unroll
  for (int j = 0; j < 4; ++j) {
    int col = n0 + wn * 64 + j * 16 + lm;
    float bv = bias[col];
#pragma unroll
    for (int i = 0; i < 8; ++i) {
      int row = m0 + wm * 128 + i * 16 + quad * 4;
#pragma unroll
      for (int r = 0; r < 4; ++r)
        out[(size_t)(row + r) * N_TOT + col] = acc[i][j][r] + bv;
    }
  }
}

extern "C" void kernel_launch(void* const* d_in, const int* in_sizes, int n_in,
                              void* d_out, int out_size, void* d_ws, size_t ws_size,
                              hipStream_t stream) {
  const float* x    = (const float*)d_in[0];  // (4,4096,4096) -> M=16384, K=4096
  const float* base = (const float*)d_in[1];  // (4096,4096) K x N
  const float* bias = (const float*)d_in[2];  // (4096,)
  const float* lA   = (const float*)d_in[3];  // (16,16)
  const float* lB   = (const float*)d_in[4];  // (16,16)
  const float* O    = (const float*)d_in[5];  // (256,256)
  float* out = (float*)d_out;

  // Workspace layout: Xb bf16 (128 MB) | Wt bf16 (32 MB) | wl f32 (1 KB)
  char* ws = (char*)d_ws;
  unsigned short* Xb = (unsigned short*)ws;
  unsigned short* Wt = (unsigned short*)(ws + (size_t)M_TOT * K_TOT * 2);
  float* wl = (float*)(ws + (size_t)M_TOT * K_TOT * 2 + (size_t)N_TOT * K_TOT * 2);

  wleft_kernel<<<1, 256, 0, stream>>>(lA, lB, wl);
  prep_w_kernel<<<dim3(N_TOT / 64, K_TOT / 64), 256, 0, stream>>>(base, O, wl, Wt);
  cvt_x_kernel<<<((size_t)M_TOT * K_TOT) / 8 / 256, 256, 0, stream>>>(x, Xb);
  gemm256_kernel<<<dim3(1024), 512, 0, stream>>>(Xb, Wt, bias, out);
}